// Round 1
// baseline (863.556 us; speedup 1.0000x reference)
//
#include <hip/hip_runtime.h>
#include <math.h>

// ---------------------------------------------------------------------------
// Fused causal self-attention, fp32 baseline.
//   x      [4,4096,1024]
//   w_qkv  [384,1024]   (out,in) -> q,k,v each [.,128]
//   w_out  [1024,128]
//   b_out  [1024]
// Pipeline: gemm_bt<0> (QKV proj, split into q/k/v ws regions)
//           flash_attn (32x32 tiles, online softmax, causal)
//           gemm_bt<1> (out proj + bias)
// ---------------------------------------------------------------------------

#define NEG_MAX 3.402823466e38f
#define SCALE_QK 0.08838834764831845f   // 128^-0.5

// C = A(MxK) * B(NxK)^T.  64x64 tile, 16-wide K step, 4x4 micro-tile.
// MODE 0: scatter cols into o0/o1/o2 (q/k/v, each row stride 128).
// MODE 1: add bias, write o0 (MxN).
template<int MODE>
__global__ __launch_bounds__(256)
void gemm_bt(const float* __restrict__ A, const float* __restrict__ B,
             float* __restrict__ o0, float* __restrict__ o1, float* __restrict__ o2,
             const float* __restrict__ bias, int M, int N, int K)
{
    __shared__ float As[16][68];   // [k][m], pad 68: 16B-aligned rows, conflict-free
    __shared__ float Bs[16][68];   // [k][n]
    const int tid = threadIdx.x;
    const int m_base = blockIdx.x * 64;
    const int n_base = blockIdx.y * 64;
    const int lr = tid >> 2;            // 0..63 tile row for staging
    const int lk = (tid & 3) << 2;      // k offset 0,4,8,12
    const int tx = tid & 15;            // micro-tile col group
    const int ty = tid >> 4;            // micro-tile row group
    const float* Arow = A + (size_t)(m_base + lr) * K + lk;
    const float* Brow = B + (size_t)(n_base + lr) * K + lk;
    float acc[4][4] = {};

    for (int kt = 0; kt < K; kt += 16) {
        float4 a4 = *(const float4*)(Arow + kt);
        float4 b4 = *(const float4*)(Brow + kt);
        __syncthreads();  // previous iteration's reads complete before overwrite
        As[lk+0][lr] = a4.x; As[lk+1][lr] = a4.y; As[lk+2][lr] = a4.z; As[lk+3][lr] = a4.w;
        Bs[lk+0][lr] = b4.x; Bs[lk+1][lr] = b4.y; Bs[lk+2][lr] = b4.z; Bs[lk+3][lr] = b4.w;
        __syncthreads();
        #pragma unroll
        for (int k = 0; k < 16; ++k) {
            float4 av = *(const float4*)&As[k][ty << 2];
            float4 bv = *(const float4*)&Bs[k][tx << 2];
            float a[4] = {av.x, av.y, av.z, av.w};
            float b[4] = {bv.x, bv.y, bv.z, bv.w};
            #pragma unroll
            for (int i = 0; i < 4; ++i)
                #pragma unroll
                for (int j = 0; j < 4; ++j)
                    acc[i][j] = fmaf(a[i], b[j], acc[i][j]);
        }
    }

    if (MODE == 0) {
        // n_base in {0,64,...,320}; 64-col tile never straddles a 128 boundary
        const int region = n_base >> 7;
        float* dst = (region == 0) ? o0 : (region == 1) ? o1 : o2;
        const int ncol = (n_base & 127) + (tx << 2);
        #pragma unroll
        for (int i = 0; i < 4; ++i) {
            const int m = m_base + (ty << 2) + i;
            float4 v = make_float4(acc[i][0], acc[i][1], acc[i][2], acc[i][3]);
            *(float4*)(dst + (size_t)m * 128 + ncol) = v;
        }
    } else {
        const int n = n_base + (tx << 2);
        float4 bv = *(const float4*)(bias + n);
        #pragma unroll
        for (int i = 0; i < 4; ++i) {
            const int m = m_base + (ty << 2) + i;
            float4 v = make_float4(acc[i][0] + bv.x, acc[i][1] + bv.y,
                                   acc[i][2] + bv.z, acc[i][3] + bv.w);
            *(float4*)(o0 + (size_t)m * N + n) = v;
        }
    }
}

// Flash attention: one block = one (batch, 32-row query tile). D = 128.
// LDS ~55.5 KB -> 2 blocks/CU. Strided 2x2 micro-tiles keep LDS reads <=2-way.
__global__ __launch_bounds__(256)
void flash_attn(const float* __restrict__ Qg, const float* __restrict__ Kg,
                const float* __restrict__ Vg, float* __restrict__ Og)
{
    __shared__ float Qs[32][132];   // pad 132: 16B-aligned, stride==4 mod 32
    __shared__ float Ks[32][132];
    __shared__ float Vs[32][132];
    __shared__ float Ss[32][36];
    __shared__ float alphaS[32];
    __shared__ float lS[32];

    const int tid = threadIdx.x;
    const int bx  = blockIdx.x;
    const int b   = bx & 3;
    const int bi  = bx >> 2;                       // 0..127
    // pairing schedule: first 256 blocks take odd q-tiles descending, next 256
    // take evens ascending -> co-resident pairs have ~constant total work
    const int qt  = (bi < 64) ? (127 - 2 * bi) : (2 * (bi - 64));
    const size_t base = (size_t)b * 4096 * 128;

    // load Q tile (coalesced float4)
    {
        const float* src = Qg + base + (size_t)qt * 32 * 128;
        #pragma unroll
        for (int it = 0; it < 4; ++it) {
            int idx = tid + it * 256;              // 0..1023
            int r = idx >> 5, c4 = (idx & 31) << 2;
            *(float4*)&Qs[r][c4] = *(const float4*)(src + r * 128 + c4);
        }
    }

    const int tx = tid & 15;        // S cols {tx, tx+16}; O cols {4tx.., 4tx+64..}
    const int ty = tid >> 4;        // S/O rows {ty, ty+16}
    const int sr = tid >> 3;        // softmax row 0..31
    const int sj = tid & 7;         // softmax col group (4 cols each)

    float o[2][8] = {};             // O accumulator: rows {ty,ty+16} x 8 cols
    float m_row = -INFINITY;        // online-softmax state, redundant in 8 lanes/row
    float l_row = 0.f;

    for (int kt = 0; kt <= qt; ++kt) {
        __syncthreads();            // prior PV reads done before K/V overwrite
        {
            const float* ksrc = Kg + base + (size_t)kt * 32 * 128;
            const float* vsrc = Vg + base + (size_t)kt * 32 * 128;
            #pragma unroll
            for (int it = 0; it < 4; ++it) {
                int idx = tid + it * 256;
                int r = idx >> 5, c4 = (idx & 31) << 2;
                *(float4*)&Ks[r][c4] = *(const float4*)(ksrc + r * 128 + c4);
                *(float4*)&Vs[r][c4] = *(const float4*)(vsrc + r * 128 + c4);
            }
        }
        __syncthreads();

        // S = Q K^T (2x2 strided micro-tile, float4 over k)
        {
            float s00 = 0.f, s01 = 0.f, s10 = 0.f, s11 = 0.f;
            #pragma unroll 8
            for (int k = 0; k < 128; k += 4) {
                float4 q0 = *(const float4*)&Qs[ty][k];
                float4 q1 = *(const float4*)&Qs[ty + 16][k];
                float4 k0 = *(const float4*)&Ks[tx][k];
                float4 k1 = *(const float4*)&Ks[tx + 16][k];
                s00 = fmaf(q0.x, k0.x, fmaf(q0.y, k0.y, fmaf(q0.z, k0.z, fmaf(q0.w, k0.w, s00))));
                s01 = fmaf(q0.x, k1.x, fmaf(q0.y, k1.y, fmaf(q0.z, k1.z, fmaf(q0.w, k1.w, s01))));
                s10 = fmaf(q1.x, k0.x, fmaf(q1.y, k0.y, fmaf(q1.z, k0.z, fmaf(q1.w, k0.w, s10))));
                s11 = fmaf(q1.x, k1.x, fmaf(q1.y, k1.y, fmaf(q1.z, k1.z, fmaf(q1.w, k1.w, s11))));
            }
            float v00 = s00 * SCALE_QK, v01 = s01 * SCALE_QK;
            float v10 = s10 * SCALE_QK, v11 = s11 * SCALE_QK;
            if (kt == qt) {         // diagonal tile: mask local col > local row
                const int r0 = ty, r1 = ty + 16, c0 = tx, c1 = tx + 16;
                if (c0 > r0) v00 = -NEG_MAX;
                if (c1 > r0) v01 = -NEG_MAX;   // always true (c1>=16>r0<=15)
                if (c0 > r1) v10 = -NEG_MAX;
                if (c1 > r1) v11 = -NEG_MAX;
            }
            Ss[ty][tx]           = v00;
            Ss[ty][tx + 16]      = v01;
            Ss[ty + 16][tx]      = v10;
            Ss[ty + 16][tx + 16] = v11;
        }
        __syncthreads();

        // online softmax over this 32-col tile (8 lanes per row)
        {
            float4 p = *(const float4*)&Ss[sr][sj << 2];
            float mx = fmaxf(fmaxf(p.x, p.y), fmaxf(p.z, p.w));
            #pragma unroll
            for (int d = 1; d < 8; d <<= 1) mx = fmaxf(mx, __shfl_xor(mx, d));
            const float m_new = fmaxf(m_row, mx);
            const float alpha = __expf(m_row - m_new);   // exp(-inf)=0 on first tile
            p.x = __expf(p.x - m_new);
            p.y = __expf(p.y - m_new);
            p.z = __expf(p.z - m_new);
            p.w = __expf(p.w - m_new);
            float ls = p.x + p.y + p.z + p.w;
            #pragma unroll
            for (int d = 1; d < 8; d <<= 1) ls += __shfl_xor(ls, d);
            l_row = l_row * alpha + ls;
            m_row = m_new;
            *(float4*)&Ss[sr][sj << 2] = p;              // P overwrites S
            if (sj == 0) alphaS[sr] = alpha;
        }
        __syncthreads();

        // O = O*alpha + P V
        {
            const float a0 = alphaS[ty];
            const float a1 = alphaS[ty + 16];
            #pragma unroll
            for (int c = 0; c < 8; ++c) { o[0][c] *= a0; o[1][c] *= a1; }
            #pragma unroll 4
            for (int j = 0; j < 32; ++j) {
                const float p0 = Ss[ty][j];
                const float p1 = Ss[ty + 16][j];
                float va[8];
                *(float4*)&va[0] = *(const float4*)&Vs[j][tx << 2];
                *(float4*)&va[4] = *(const float4*)&Vs[j][(tx << 2) + 64];
                #pragma unroll
                for (int c = 0; c < 8; ++c) {
                    o[0][c] = fmaf(p0, va[c], o[0][c]);
                    o[1][c] = fmaf(p1, va[c], o[1][c]);
                }
            }
        }
    }

    __syncthreads();
    if (sj == 0) lS[sr] = l_row;
    __syncthreads();
    {
        const float l0 = lS[ty], l1 = lS[ty + 16];
        float* dst0 = Og + base + (size_t)(qt * 32 + ty) * 128;
        float* dst1 = Og + base + (size_t)(qt * 32 + ty + 16) * 128;
        *(float4*)(dst0 + (tx << 2))      = make_float4(o[0][0]/l0, o[0][1]/l0, o[0][2]/l0, o[0][3]/l0);
        *(float4*)(dst0 + (tx << 2) + 64) = make_float4(o[0][4]/l0, o[0][5]/l0, o[0][6]/l0, o[0][7]/l0);
        *(float4*)(dst1 + (tx << 2))      = make_float4(o[1][0]/l1, o[1][1]/l1, o[1][2]/l1, o[1][3]/l1);
        *(float4*)(dst1 + (tx << 2) + 64) = make_float4(o[1][4]/l1, o[1][5]/l1, o[1][6]/l1, o[1][7]/l1);
    }
}

extern "C" void kernel_launch(void* const* d_in, const int* in_sizes, int n_in,
                              void* d_out, int out_size, void* d_ws, size_t ws_size,
                              hipStream_t stream)
{
    (void)in_sizes; (void)n_in; (void)out_size; (void)ws_size;
    const float* x     = (const float*)d_in[0];
    const float* w_qkv = (const float*)d_in[1];
    const float* w_out = (const float*)d_in[2];
    const float* b_out = (const float*)d_in[3];
    float* out = (float*)d_out;
    float* ws  = (float*)d_ws;

    const size_t NQ = (size_t)16384 * 128;     // one of q/k/v/attn_out
    float* qws  = ws;
    float* kws  = ws + NQ;
    float* vws  = ws + 2 * NQ;
    float* aout = ws + 3 * NQ;                 // total 33.6 MB of d_ws

    // QKV projection: [16384,1024] x [384,1024]^T -> q/k/v
    hipLaunchKernelGGL((gemm_bt<0>), dim3(256, 6), dim3(256), 0, stream,
                       x, w_qkv, qws, kws, vws, (const float*)nullptr, 16384, 384, 1024);
    // causal flash attention
    hipLaunchKernelGGL(flash_attn, dim3(512), dim3(256), 0, stream,
                       qws, kws, vws, aout);
    // output projection + bias: [16384,128] x [1024,128]^T
    hipLaunchKernelGGL((gemm_bt<1>), dim3(256, 16), dim3(256), 0, stream,
                       aout, w_out, out, (float*)nullptr, (float*)nullptr, b_out, 16384, 1024, 128);
}

// Round 3
// 313.917 us; speedup vs baseline: 2.7509x; 2.7509x over previous
//
#include <hip/hip_runtime.h>
#include <math.h>

// ---------------------------------------------------------------------------
// bf16-MFMA pipeline:
//   gemm_qkv    : x[16384,1024] x w_qkv[384,1024]^T -> q,k,v bf16 [16384,128]
//   transpose_v : v -> vt bf16 [4][128][4096]
//   flash_attn  : causal online-softmax attention, 16x16x32 bf16 MFMA
//   gemm_out    : o[16384,128] x w_out[1024,128]^T + bias -> out fp32
// ---------------------------------------------------------------------------

typedef __attribute__((ext_vector_type(8))) short bf16x8;   // 8 bf16 = 4 VGPR
typedef __attribute__((ext_vector_type(4))) short bf16x4;   // 4 bf16 = 8 B
typedef __attribute__((ext_vector_type(4))) float f32x4;

#define FA_SCALE 0.08838834764831845f   // 128^-0.5

__device__ __forceinline__ unsigned short f2bf(float f) {
    union { float f; unsigned u; } v; v.f = f;
    unsigned r = v.u + 0x7FFFu + ((v.u >> 16) & 1u);    // RNE
    return (unsigned short)(r >> 16);
}

__device__ __forceinline__ f32x4 mfma16(bf16x8 a, bf16x8 b, f32x4 c) {
    return __builtin_amdgcn_mfma_f32_16x16x32_bf16(a, b, c, 0, 0, 0);
}

// async global->LDS, 16B per lane, dest = lds_base + lane*16
__device__ __forceinline__ void gl2lds16(const void* g, void* l) {
    __builtin_amdgcn_global_load_lds(
        (const __attribute__((address_space(1))) unsigned int*)g,
        (__attribute__((address_space(3))) unsigned int*)l, 16, 0, 0);
}

// ---------------------------------------------------------------------------
// QKV projection. BM=128, BN=128, BK=32. grid (128,3) x 256 thr.
// LDS frag-major: [chunk(k8) 0..3][row 0..127][8 bf16]
// ---------------------------------------------------------------------------
__global__ __launch_bounds__(256)
void gemm_qkv(const float* __restrict__ X, const float* __restrict__ W,
              unsigned short* __restrict__ q, unsigned short* __restrict__ k,
              unsigned short* __restrict__ v)
{
    __shared__ unsigned short Asl[4 * 128 * 8];
    __shared__ unsigned short Bsl[4 * 128 * 8];
    const int tid = threadIdx.x;
    const int mb = blockIdx.x * 128;
    const int nb = blockIdx.y * 128;
    const int wv = tid >> 6, lane = tid & 63;
    const int wr = (wv >> 1) * 64, wc = (wv & 1) * 64;   // wave's 64x64 region
    const int lm = lane & 15, quad = lane >> 4;
    const int sr = tid >> 2, sc = tid & 3;               // staging row / chunk

    f32x4 acc[4][4];
    #pragma unroll
    for (int i = 0; i < 4; ++i)
        #pragma unroll
        for (int j = 0; j < 4; ++j) acc[i][j] = f32x4{0.f, 0.f, 0.f, 0.f};

    for (int kt = 0; kt < 1024; kt += 32) {
        __syncthreads();
        #pragma unroll
        for (int h = 0; h < 2; ++h) {
            const int row = sr + h * 64;
            const float* g = X + (size_t)(mb + row) * 1024 + kt + sc * 8;
            float4 x0 = *(const float4*)g, x1 = *(const float4*)(g + 4);
            bf16x8 pk;
            pk[0] = (short)f2bf(x0.x); pk[1] = (short)f2bf(x0.y);
            pk[2] = (short)f2bf(x0.z); pk[3] = (short)f2bf(x0.w);
            pk[4] = (short)f2bf(x1.x); pk[5] = (short)f2bf(x1.y);
            pk[6] = (short)f2bf(x1.z); pk[7] = (short)f2bf(x1.w);
            *(bf16x8*)&Asl[(sc * 128 + row) * 8] = pk;
            const float* gw = W + (size_t)(nb + row) * 1024 + kt + sc * 8;
            float4 w0 = *(const float4*)gw, w1 = *(const float4*)(gw + 4);
            bf16x8 pw;
            pw[0] = (short)f2bf(w0.x); pw[1] = (short)f2bf(w0.y);
            pw[2] = (short)f2bf(w0.z); pw[3] = (short)f2bf(w0.w);
            pw[4] = (short)f2bf(w1.x); pw[5] = (short)f2bf(w1.y);
            pw[6] = (short)f2bf(w1.z); pw[7] = (short)f2bf(w1.w);
            *(bf16x8*)&Bsl[(sc * 128 + row) * 8] = pw;
        }
        __syncthreads();
        bf16x8 af[4], bfr[4];
        #pragma unroll
        for (int i = 0; i < 4; ++i)
            af[i] = *(const bf16x8*)&Asl[(quad * 128 + wr + i * 16 + lm) * 8];
        #pragma unroll
        for (int j = 0; j < 4; ++j)
            bfr[j] = *(const bf16x8*)&Bsl[(quad * 128 + wc + j * 16 + lm) * 8];
        #pragma unroll
        for (int i = 0; i < 4; ++i)
            #pragma unroll
            for (int j = 0; j < 4; ++j)
                acc[i][j] = mfma16(af[i], bfr[j], acc[i][j]);
    }

    unsigned short* dst = (nb == 0) ? q : (nb == 128) ? k : v;
    #pragma unroll
    for (int i = 0; i < 4; ++i)
        #pragma unroll
        for (int j = 0; j < 4; ++j) {
            const int col = wc + j * 16 + lm;
            #pragma unroll
            for (int r = 0; r < 4; ++r) {
                const int m = mb + wr + i * 16 + quad * 4 + r;
                dst[(size_t)m * 128 + col] = f2bf(acc[i][j][r]);
            }
        }
}

// ---------------------------------------------------------------------------
// V transpose: v[4][4096][128] -> vt[4][128][4096]. grid 256 x 256 thr.
// ---------------------------------------------------------------------------
__global__ __launch_bounds__(256)
void transpose_v(const unsigned short* __restrict__ V, unsigned short* __restrict__ Vt)
{
    __shared__ unsigned short T[128 * 72];   // [col][key], stride 72 (16B-aligned)
    const int tid = threadIdx.x;
    const int b  = blockIdx.x >> 6;
    const int kb = (blockIdx.x & 63) * 64;
    const unsigned short* src = V + ((size_t)b * 4096 + kb) * 128;
    #pragma unroll
    for (int i = 0; i < 4; ++i) {
        const int idx = tid + i * 256;               // 8-elem chunk id
        const int key = idx >> 4, c8 = (idx & 15) * 8;
        bf16x8 d = *(const bf16x8*)(src + key * 128 + c8);
        #pragma unroll
        for (int e = 0; e < 8; ++e) T[(c8 + e) * 72 + key] = (unsigned short)d[e];
    }
    __syncthreads();
    unsigned short* dst = Vt + (size_t)b * 128 * 4096 + kb;
    #pragma unroll
    for (int i = 0; i < 4; ++i) {
        const int o = tid + i * 256;
        const int col = o >> 3, k8 = (o & 7) * 8;
        bf16x8 d = *(const bf16x8*)&T[col * 72 + k8];
        *(bf16x8*)(dst + (size_t)col * 4096 + k8) = d;
    }
}

// ---------------------------------------------------------------------------
// Flash attention. Br=32, Bc=64, D=128. grid 512 x 256 thr (4 waves).
// Q frags in registers; K/V^T staged frag-major via global_load_lds.
// ---------------------------------------------------------------------------
__global__ __launch_bounds__(256)
void flash_attn(const unsigned short* __restrict__ Qg, const unsigned short* __restrict__ Kg,
                const unsigned short* __restrict__ Vtg, unsigned short* __restrict__ Og)
{
    __shared__ unsigned short Klds[16 * 64 * 8];    // [chunk][key][8]   16 KB
    __shared__ unsigned short Vlds[8 * 128 * 8];    // [chunk][col][8]   16 KB
    __shared__ __align__(16) float Ss[32 * 68];     // scores             8.7 KB
    __shared__ unsigned short Plds[8 * 32 * 8];     // P frag-major       4 KB
    __shared__ __align__(16) float alphaS[32];
    __shared__ __align__(16) float lS[32];

    const int tid = threadIdx.x;
    const int wv = tid >> 6, lane = tid & 63;
    const int lm = lane & 15, quad = lane >> 4;

    const int b  = blockIdx.x & 3;
    const int bi = blockIdx.x >> 2;
    // pairing: odd q-tiles descending then even ascending -> balanced CU pairs
    const int qt = (bi < 64) ? (127 - 2 * bi) : (2 * (bi - 64));

    const size_t kvbase = (size_t)b * 4096 * 128;
    const size_t vtbase = (size_t)b * 128 * 4096;
    const size_t qrow0  = kvbase + (size_t)qt * 32 * 128;

    // stage Q tile (16 chunks) into Klds, then pull frags to registers.
    // one gl2lds16 call covers chunks {2id, 2id+1} (lanes 0..31 / 32..63),
    // chunk c lives at Klds + c*256 -> call base = Klds + id*512.
    #pragma unroll
    for (int i = 0; i < 2; ++i) {
        const int id = wv * 2 + i;   // chunk pair id 0..7
        const unsigned short* g = Qg + qrow0 + (size_t)(lane & 31) * 128
                                  + (2 * id + (lane >> 5)) * 8;
        gl2lds16(g, &Klds[id * 512]);
    }
    __syncthreads();
    bf16x8 qf[2][4];
    #pragma unroll
    for (int t = 0; t < 2; ++t)
        #pragma unroll
        for (int s = 0; s < 4; ++s)
            qf[t][s] = *(const bf16x8*)&Klds[((s * 4 + quad) * 32 + t * 16 + lm) * 8];

    f32x4 oacc[2][2];
    #pragma unroll
    for (int t = 0; t < 2; ++t)
        #pragma unroll
        for (int c = 0; c < 2; ++c) oacc[t][c] = f32x4{0.f, 0.f, 0.f, 0.f};
    float m_run = -INFINITY, l_run = 0.f;
    const int srow = tid >> 3, sj = tid & 7;

    const int nkv = (qt >> 1) + 1;
    for (int kt2 = 0; kt2 < nkv; ++kt2) {
        __syncthreads();                       // prior-iter LDS consumers done
        #pragma unroll
        for (int i = 0; i < 4; ++i) {          // K tile: chunks wv*4..wv*4+3
            const int c = wv * 4 + i;
            const unsigned short* g = Kg + kvbase + (size_t)(kt2 * 64 + lane) * 128 + c * 8;
            gl2lds16(g, &Klds[c * 512]);
        }
        #pragma unroll
        for (int i = 0; i < 4; ++i) {          // V^T tile
            const int id = wv * 4 + i;
            const int c = id >> 1, h = id & 1;
            const unsigned short* g = Vtg + vtbase + (size_t)(h * 64 + lane) * 4096
                                      + kt2 * 64 + c * 8;
            gl2lds16(g, &Vlds[c * 1024 + h * 512]);
        }
        __syncthreads();

        // S = Q K^T  (wave's 32x16 strip at cols wv*16..)
        f32x4 sacc[2] = {f32x4{0.f,0.f,0.f,0.f}, f32x4{0.f,0.f,0.f,0.f}};
        #pragma unroll
        for (int s = 0; s < 4; ++s) {
            bf16x8 kb = *(const bf16x8*)&Klds[((s * 4 + quad) * 64 + wv * 16 + lm) * 8];
            sacc[0] = mfma16(qf[0][s], kb, sacc[0]);
            sacc[1] = mfma16(qf[1][s], kb, sacc[1]);
        }
        const bool lastkv = (kt2 == nkv - 1);
        #pragma unroll
        for (int t = 0; t < 2; ++t)
            #pragma unroll
            for (int r = 0; r < 4; ++r) {
                const int row = t * 16 + quad * 4 + r;
                const int col = wv * 16 + lm;
                float sv = sacc[t][r] * FA_SCALE;
                if (lastkv && (kt2 * 64 + col > qt * 32 + row)) sv = -INFINITY;
                Ss[row * 68 + col] = sv;
            }
        __syncthreads();

        // online softmax: 8 lanes per row
        {
            float p[8];
            *(float4*)&p[0] = *(const float4*)&Ss[srow * 68 + sj * 4];
            *(float4*)&p[4] = *(const float4*)&Ss[srow * 68 + 32 + sj * 4];
            float mx = p[0];
            #pragma unroll
            for (int e = 1; e < 8; ++e) mx = fmaxf(mx, p[e]);
            #pragma unroll
            for (int d = 1; d < 8; d <<= 1) mx = fmaxf(mx, __shfl_xor(mx, d));
            const float m_new = fmaxf(m_run, mx);
            const float alpha = __expf(m_run - m_new);
            float sum = 0.f;
            bf16x4 lo, hi;
            #pragma unroll
            for (int e = 0; e < 4; ++e) {
                p[e] = __expf(p[e] - m_new); sum += p[e]; lo[e] = (short)f2bf(p[e]);
            }
            #pragma unroll
            for (int e = 4; e < 8; ++e) {
                p[e] = __expf(p[e] - m_new); sum += p[e]; hi[e - 4] = (short)f2bf(p[e]);
            }
            #pragma unroll
            for (int d = 1; d < 8; d <<= 1) sum += __shfl_xor(sum, d);
            l_run = l_run * alpha + sum;
            m_run = m_new;
            *(bf16x4*)&Plds[((sj >> 1) * 32 + srow) * 8 + (sj & 1) * 4] = lo;
            *(bf16x4*)&Plds[(((sj >> 1) + 4) * 32 + srow) * 8 + (sj & 1) * 4] = hi;
            if (sj == 0) alphaS[srow] = alpha;
        }
        __syncthreads();

        // O = O*alpha + P V   (wave owns O cols wv*32..wv*32+31)
        #pragma unroll
        for (int t = 0; t < 2; ++t) {
            f32x4 a4 = *(const f32x4*)&alphaS[t * 16 + quad * 4];
            oacc[t][0] *= a4;
            oacc[t][1] *= a4;
        }
        #pragma unroll
        for (int s = 0; s < 2; ++s) {
            bf16x8 pf[2], vf[2];
            #pragma unroll
            for (int t = 0; t < 2; ++t)
                pf[t] = *(const bf16x8*)&Plds[((s * 4 + quad) * 32 + t * 16 + lm) * 8];
            #pragma unroll
            for (int ct = 0; ct < 2; ++ct)
                vf[ct] = *(const bf16x8*)&Vlds[((s * 4 + quad) * 128 + wv * 32 + ct * 16 + lm) * 8];
            #pragma unroll
            for (int t = 0; t < 2; ++t)
                #pragma unroll
                for (int ct = 0; ct < 2; ++ct)
                    oacc[t][ct] = mfma16(pf[t], vf[ct], oacc[t][ct]);
        }
    }

    if (sj == 0) lS[srow] = l_run;
    __syncthreads();
    #pragma unroll
    for (int t = 0; t < 2; ++t) {
        f32x4 l4 = *(const f32x4*)&lS[t * 16 + quad * 4];
        #pragma unroll
        for (int ct = 0; ct < 2; ++ct)
            #pragma unroll
            for (int r = 0; r < 4; ++r) {
                const int row = t * 16 + quad * 4 + r;
                const int col = wv * 32 + ct * 16 + lm;
                Og[qrow0 + (size_t)row * 128 + col] = f2bf(oacc[t][ct][r] / l4[r]);
            }
    }
}

// ---------------------------------------------------------------------------
// Output projection + bias. BM=128, BN=128, K=128. grid (128,8) x 256 thr.
// ---------------------------------------------------------------------------
__global__ __launch_bounds__(256)
void gemm_out(const unsigned short* __restrict__ Ain, const float* __restrict__ W,
              const float* __restrict__ bias, float* __restrict__ out)
{
    __shared__ unsigned short Bsl[16 * 128 * 8];   // whole W tile (K=128), 32 KB
    __shared__ unsigned short Asl[4 * 128 * 8];    // per-BK32 A, 8 KB
    const int tid = threadIdx.x;
    const int mb = blockIdx.x * 128;
    const int nb = blockIdx.y * 128;
    const int wv = tid >> 6, lane = tid & 63;
    const int wr = (wv >> 1) * 64, wc = (wv & 1) * 64;
    const int lm = lane & 15, quad = lane >> 4;

    {   // stage W once (fp32 -> bf16)
        const int r = tid >> 1;
        #pragma unroll
        for (int i = 0; i < 8; ++i) {
            const int c = (tid & 1) * 8 + i;
            const float* g = W + (size_t)(nb + r) * 128 + c * 8;
            float4 w0 = *(const float4*)g, w1 = *(const float4*)(g + 4);
            bf16x8 pw;
            pw[0] = (short)f2bf(w0.x); pw[1] = (short)f2bf(w0.y);
            pw[2] = (short)f2bf(w0.z); pw[3] = (short)f2bf(w0.w);
            pw[4] = (short)f2bf(w1.x); pw[5] = (short)f2bf(w1.y);
            pw[6] = (short)f2bf(w1.z); pw[7] = (short)f2bf(w1.w);
            *(bf16x8*)&Bsl[(c * 128 + r) * 8] = pw;
        }
    }

    f32x4 acc[4][4];
    #pragma unroll
    for (int i = 0; i < 4; ++i)
        #pragma unroll
        for (int j = 0; j < 4; ++j) acc[i][j] = f32x4{0.f, 0.f, 0.f, 0.f};

    for (int kt = 0; kt < 4; ++kt) {
        __syncthreads();
        #pragma unroll
        for (int i = 0; i < 2; ++i) {
            const int id = wv * 2 + i;
            const int c = id >> 1, h = id & 1;
            const unsigned short* g = Ain + (size_t)(mb + h * 64 + lane) * 128 + kt * 32 + c * 8;
            gl2lds16(g, &Asl[c * 1024 + h * 512]);
        }
        __syncthreads();
        bf16x8 af[4], bfr[4];
        #pragma unroll
        for (int i = 0; i < 4; ++i)
            af[i] = *(const bf16x8*)&Asl[(quad * 128 + wr + i * 16 + lm) * 8];
        #pragma unroll
        for (int j = 0; j < 4; ++j)
            bfr[j] = *(const bf16x8*)&Bsl[((kt * 4 + quad) * 128 + wc + j * 16 + lm) * 8];
        #pragma unroll
        for (int i = 0; i < 4; ++i)
            #pragma unroll
            for (int j = 0; j < 4; ++j)
                acc[i][j] = mfma16(af[i], bfr[j], acc[i][j]);
    }

    #pragma unroll
    for (int j = 0; j < 4; ++j) {
        const int col = nb + wc + j * 16 + lm;
        const float bv = bias[col];
        #pragma unroll
        for (int i = 0; i < 4; ++i)
            #pragma unroll
            for (int r = 0; r < 4; ++r) {
                const int m = mb + wr + i * 16 + quad * 4 + r;
                out[(size_t)m * 1024 + col] = acc[i][j][r] + bv;
            }
    }
}

// ---------------------------------------------------------------------------
extern "C" void kernel_launch(void* const* d_in, const int* in_sizes, int n_in,
                              void* d_out, int out_size, void* d_ws, size_t ws_size,
                              hipStream_t stream)
{
    (void)in_sizes; (void)n_in; (void)out_size; (void)ws_size;
    const float* x     = (const float*)d_in[0];
    const float* w_qkv = (const float*)d_in[1];
    const float* w_out = (const float*)d_in[2];
    const float* b_out = (const float*)d_in[3];
    float* out = (float*)d_out;
    unsigned short* ws = (unsigned short*)d_ws;

    const size_t NE = (size_t)16384 * 128;
    unsigned short* q  = ws;
    unsigned short* k  = ws + NE;
    unsigned short* v  = ws + 2 * NE;
    unsigned short* vt = ws + 3 * NE;
    unsigned short* o  = ws + 4 * NE;   // 21 MB total

    hipLaunchKernelGGL(gemm_qkv,    dim3(128, 3), dim3(256), 0, stream, x, w_qkv, q, k, v);
    hipLaunchKernelGGL(transpose_v, dim3(256),    dim3(256), 0, stream, v, vt);
    hipLaunchKernelGGL(flash_attn,  dim3(512),    dim3(256), 0, stream, q, k, vt, o);
    hipLaunchKernelGGL(gemm_out,    dim3(128, 8), dim3(256), 0, stream, o, w_out, b_out, out);
}

// Round 4
// 282.018 us; speedup vs baseline: 3.0621x; 1.1131x over previous
//
#include <hip/hip_runtime.h>
#include <math.h>

// ---------------------------------------------------------------------------
// bf16-MFMA pipeline v3:
//   gemm_qkv    : x[16384,1024] x w_qkv[384,1024]^T -> q,k,v bf16 [16384,128]
//   transpose_v : v -> vt bf16 [4][128][4096]
//   flash_attn2 : causal attention, 2-wave blocks, in-register softmax,
//                 KV-split x2 with bf16 partials (Opart) + m/l
//   fa_combine  : merge the two KV-halves -> o bf16
//   gemm_out    : o[16384,128] x w_out[1024,128]^T + bias -> out fp32
// ---------------------------------------------------------------------------

typedef __attribute__((ext_vector_type(8))) short bf16x8;   // 8 bf16 = 4 VGPR
typedef __attribute__((ext_vector_type(4))) short bf16x4;   // 4 bf16 = 8 B
typedef __attribute__((ext_vector_type(4))) float f32x4;

#define FA_SCALE 0.08838834764831845f   // 128^-0.5

__device__ __forceinline__ unsigned short f2bf(float f) {
    union { float f; unsigned u; } v; v.f = f;
    unsigned r = v.u + 0x7FFFu + ((v.u >> 16) & 1u);    // RNE
    return (unsigned short)(r >> 16);
}
__device__ __forceinline__ float bf2f(unsigned short h) {
    union { unsigned u; float f; } v; v.u = ((unsigned)h) << 16;
    return v.f;
}
__device__ __forceinline__ f32x4 mfma16(bf16x8 a, bf16x8 b, f32x4 c) {
    return __builtin_amdgcn_mfma_f32_16x16x32_bf16(a, b, c, 0, 0, 0);
}
__device__ __forceinline__ void gl2lds16(const void* g, void* l) {
    __builtin_amdgcn_global_load_lds(
        (const __attribute__((address_space(1))) unsigned int*)g,
        (__attribute__((address_space(3))) unsigned int*)l, 16, 0, 0);
}
__device__ __forceinline__ f32x4 vmax4(f32x4 a, f32x4 b) {
    return f32x4{fmaxf(a[0], b[0]), fmaxf(a[1], b[1]),
                 fmaxf(a[2], b[2]), fmaxf(a[3], b[3])};
}

// ---------------------------------------------------------------------------
// QKV projection (unchanged from round 2). BM=128,BN=128,BK=32. grid(128,3)x256
// ---------------------------------------------------------------------------
__global__ __launch_bounds__(256)
void gemm_qkv(const float* __restrict__ X, const float* __restrict__ W,
              unsigned short* __restrict__ q, unsigned short* __restrict__ k,
              unsigned short* __restrict__ v)
{
    __shared__ unsigned short Asl[4 * 128 * 8];
    __shared__ unsigned short Bsl[4 * 128 * 8];
    const int tid = threadIdx.x;
    const int mb = blockIdx.x * 128;
    const int nb = blockIdx.y * 128;
    const int wv = tid >> 6, lane = tid & 63;
    const int wr = (wv >> 1) * 64, wc = (wv & 1) * 64;
    const int lm = lane & 15, quad = lane >> 4;
    const int sr = tid >> 2, sc = tid & 3;

    f32x4 acc[4][4];
    #pragma unroll
    for (int i = 0; i < 4; ++i)
        #pragma unroll
        for (int j = 0; j < 4; ++j) acc[i][j] = f32x4{0.f, 0.f, 0.f, 0.f};

    for (int kt = 0; kt < 1024; kt += 32) {
        __syncthreads();
        #pragma unroll
        for (int h = 0; h < 2; ++h) {
            const int row = sr + h * 64;
            const float* g = X + (size_t)(mb + row) * 1024 + kt + sc * 8;
            float4 x0 = *(const float4*)g, x1 = *(const float4*)(g + 4);
            bf16x8 pk;
            pk[0] = (short)f2bf(x0.x); pk[1] = (short)f2bf(x0.y);
            pk[2] = (short)f2bf(x0.z); pk[3] = (short)f2bf(x0.w);
            pk[4] = (short)f2bf(x1.x); pk[5] = (short)f2bf(x1.y);
            pk[6] = (short)f2bf(x1.z); pk[7] = (short)f2bf(x1.w);
            *(bf16x8*)&Asl[(sc * 128 + row) * 8] = pk;
            const float* gw = W + (size_t)(nb + row) * 1024 + kt + sc * 8;
            float4 w0 = *(const float4*)gw, w1 = *(const float4*)(gw + 4);
            bf16x8 pw;
            pw[0] = (short)f2bf(w0.x); pw[1] = (short)f2bf(w0.y);
            pw[2] = (short)f2bf(w0.z); pw[3] = (short)f2bf(w0.w);
            pw[4] = (short)f2bf(w1.x); pw[5] = (short)f2bf(w1.y);
            pw[6] = (short)f2bf(w1.z); pw[7] = (short)f2bf(w1.w);
            *(bf16x8*)&Bsl[(sc * 128 + row) * 8] = pw;
        }
        __syncthreads();
        bf16x8 af[4], bfr[4];
        #pragma unroll
        for (int i = 0; i < 4; ++i)
            af[i] = *(const bf16x8*)&Asl[(quad * 128 + wr + i * 16 + lm) * 8];
        #pragma unroll
        for (int j = 0; j < 4; ++j)
            bfr[j] = *(const bf16x8*)&Bsl[(quad * 128 + wc + j * 16 + lm) * 8];
        #pragma unroll
        for (int i = 0; i < 4; ++i)
            #pragma unroll
            for (int j = 0; j < 4; ++j)
                acc[i][j] = mfma16(af[i], bfr[j], acc[i][j]);
    }

    unsigned short* dst = (nb == 0) ? q : (nb == 128) ? k : v;
    #pragma unroll
    for (int i = 0; i < 4; ++i)
        #pragma unroll
        for (int j = 0; j < 4; ++j) {
            const int col = wc + j * 16 + lm;
            #pragma unroll
            for (int r = 0; r < 4; ++r) {
                const int m = mb + wr + i * 16 + quad * 4 + r;
                dst[(size_t)m * 128 + col] = f2bf(acc[i][j][r]);
            }
        }
}

// ---------------------------------------------------------------------------
// V transpose (unchanged). grid 256 x 256 thr.
// ---------------------------------------------------------------------------
__global__ __launch_bounds__(256)
void transpose_v(const unsigned short* __restrict__ V, unsigned short* __restrict__ Vt)
{
    __shared__ unsigned short T[128 * 72];
    const int tid = threadIdx.x;
    const int b  = blockIdx.x >> 6;
    const int kb = (blockIdx.x & 63) * 64;
    const unsigned short* src = V + ((size_t)b * 4096 + kb) * 128;
    #pragma unroll
    for (int i = 0; i < 4; ++i) {
        const int idx = tid + i * 256;
        const int key = idx >> 4, c8 = (idx & 15) * 8;
        bf16x8 d = *(const bf16x8*)(src + key * 128 + c8);
        #pragma unroll
        for (int e = 0; e < 8; ++e) T[(c8 + e) * 72 + key] = (unsigned short)d[e];
    }
    __syncthreads();
    unsigned short* dst = Vt + (size_t)b * 128 * 4096 + kb;
    #pragma unroll
    for (int i = 0; i < 4; ++i) {
        const int o = tid + i * 256;
        const int col = o >> 3, k8 = (o & 7) * 8;
        bf16x8 d = *(const bf16x8*)&T[col * 72 + k8];
        *(bf16x8*)(dst + (size_t)col * 4096 + k8) = d;
    }
}

// ---------------------------------------------------------------------------
// Flash attention v2: 128 thr (2 waves), wave owns 16 Q-rows x all keys.
// In-register online softmax on MFMA C-layout (row = quad's 16 lanes).
// KV-split x2: block (b,qt,h) covers half the key tiles, writes bf16
// unnormalized O-partial + per-row (m,l).
// ---------------------------------------------------------------------------
__global__ __launch_bounds__(128)
void flash_attn2(const unsigned short* __restrict__ Qg, const unsigned short* __restrict__ Kg,
                 const unsigned short* __restrict__ Vtg,
                 unsigned short* __restrict__ Opart, float* __restrict__ Ml)
{
    __shared__ unsigned short Klds[16 * 64 * 8];    // [chunk d/8][key][8]  16 KB
    __shared__ unsigned short Vlds[8 * 128 * 8];    // [chunk key/8][d][8]  16 KB
    __shared__ unsigned short Plds[2 * 8 * 16 * 8]; // per-wave A-frag P     4 KB

    const int tid = threadIdx.x;
    const int wv = tid >> 6, lane = tid & 63;
    const int lm = lane & 15, quad = lane >> 4;

    // block -> (b, qt, h): heavy(h0,desc)/light(h1,asc) interleave for balance
    const int bx = blockIdx.x;
    const int b = bx & 3, j = bx >> 2, t = j >> 1, s = j & 1;
    const int qt = s ? t : (127 - t);
    const int h  = s;
    const int nkv = (qt + 2) >> 1;          // # of 64-key tiles
    const int nsplit = nkv >> 1;
    const int ktb = h ? nsplit : 0;
    const int kte = h ? nkv : nsplit;

    const size_t kvbase = (size_t)b * 4096 * 128;
    const size_t vtbase = (size_t)b * 128 * 4096;
    const size_t po = (((size_t)(b * 128 + qt)) * 2 + h) * 4096;   // 32x128
    const int    pm = ((b * 128 + qt) * 2 + h) * 64;

    if (ktb >= kte) {            // empty half (qt<2, h=0): neutral partial
        #pragma unroll
        for (int oc = 0; oc < 8; ++oc)
            #pragma unroll
            for (int r = 0; r < 4; ++r)
                Opart[po + (size_t)(wv * 16 + quad * 4 + r) * 128 + oc * 16 + lm] = 0;
        if (lm == 0)
            #pragma unroll
            for (int r = 0; r < 4; ++r) {
                const int row = wv * 16 + quad * 4 + r;
                Ml[pm + row] = -INFINITY;
                Ml[pm + 32 + row] = 0.f;
            }
        return;
    }

    // stage Q (32 rows x 128) into Klds frag-major, pull frags to regs
    const size_t qrow0 = kvbase + (size_t)qt * 32 * 128;
    #pragma unroll
    for (int i = 0; i < 4; ++i) {
        const int id = wv * 4 + i;           // chunk-pair 0..7
        const unsigned short* g = Qg + qrow0 + (size_t)(lane & 31) * 128
                                  + (2 * id + (lane >> 5)) * 8;
        gl2lds16(g, &Klds[id * 512]);
    }
    __syncthreads();
    bf16x8 qf[4];
    #pragma unroll
    for (int c = 0; c < 4; ++c)
        qf[c] = *(const bf16x8*)&Klds[((4 * c + quad) * 32 + wv * 16 + lm) * 8];

    f32x4 oacc[8];
    #pragma unroll
    for (int oc = 0; oc < 8; ++oc) oacc[oc] = f32x4{0.f, 0.f, 0.f, 0.f};
    f32x4 m4 = f32x4{-INFINITY, -INFINITY, -INFINITY, -INFINITY};
    f32x4 l4 = f32x4{0.f, 0.f, 0.f, 0.f};
    unsigned short* Pw = &Plds[wv * 1024];

    for (int kt = ktb; kt < kte; ++kt) {
        const int k0 = kt * 64;
        __syncthreads();                     // all waves done with prev tile / qf
        #pragma unroll
        for (int i = 0; i < 8; ++i) {        // K: chunk c region = 64 keys x 8 d
            const int c = wv * 8 + i;
            gl2lds16(Kg + kvbase + (size_t)(k0 + lane) * 128 + c * 8, &Klds[c * 512]);
        }
        #pragma unroll
        for (int i = 0; i < 8; ++i) {        // V^T: (chunk c=key/8, half hd of d)
            const int id = wv * 8 + i;
            const int c = id >> 1, hd = id & 1;
            gl2lds16(Vtg + vtbase + (size_t)(hd * 64 + lane) * 4096 + k0 + c * 8,
                     &Vlds[c * 1024 + hd * 512]);
        }
        __syncthreads();                     // vmcnt(0) drain: K/V ready

        // S = Q K^T : wave's 16 rows x 64 keys in 4 C-layout accumulators
        f32x4 sv[4];
        #pragma unroll
        for (int ct = 0; ct < 4; ++ct) {
            f32x4 acc = f32x4{0.f, 0.f, 0.f, 0.f};
            #pragma unroll
            for (int c = 0; c < 4; ++c) {
                bf16x8 kf = *(const bf16x8*)&Klds[((4 * c + quad) * 64 + ct * 16 + lm) * 8];
                acc = mfma16(qf[c], kf, acc);
            }
            sv[ct] = acc * FA_SCALE;
        }
        if (kt == nkv - 1) {                 // diagonal tile: mask key > row
            const int dgap = k0 + lm - (qt * 32 + wv * 16 + quad * 4);
            #pragma unroll
            for (int ct = 0; ct < 4; ++ct) {
                const int dg = dgap + ct * 16;
                #pragma unroll
                for (int r = 0; r < 4; ++r)
                    if (dg > r) sv[ct][r] = -INFINITY;
            }
        }
        // in-register online softmax (rows = quad's 16 lanes)
        f32x4 rmax = vmax4(vmax4(sv[0], sv[1]), vmax4(sv[2], sv[3]));
        #pragma unroll
        for (int d = 1; d < 16; d <<= 1) {
            f32x4 o;
            #pragma unroll
            for (int e = 0; e < 4; ++e) o[e] = __shfl_xor(rmax[e], d);
            rmax = vmax4(rmax, o);
        }
        const f32x4 mnew = vmax4(m4, rmax);
        f32x4 alpha, rs = f32x4{0.f, 0.f, 0.f, 0.f};
        #pragma unroll
        for (int e = 0; e < 4; ++e) alpha[e] = __expf(m4[e] - mnew[e]);
        #pragma unroll
        for (int ct = 0; ct < 4; ++ct)
            #pragma unroll
            for (int r = 0; r < 4; ++r) {
                const float p = __expf(sv[ct][r] - mnew[r]);
                sv[ct][r] = p; rs[r] += p;
            }
        #pragma unroll
        for (int d = 1; d < 16; d <<= 1) {
            f32x4 o;
            #pragma unroll
            for (int e = 0; e < 4; ++e) o[e] = __shfl_xor(rs[e], d);
            rs += o;
        }
        l4 = l4 * alpha + rs;
        m4 = mnew;
        // P -> wave-private LDS in A-frag layout: chunk=col/8, m=row, j=col%8
        #pragma unroll
        for (int ct = 0; ct < 4; ++ct) {
            const int cbase = ((ct * 2 + (lm >> 3)) * 16 + quad * 4) * 8 + (lm & 7);
            #pragma unroll
            for (int r = 0; r < 4; ++r)
                Pw[cbase + r * 8] = f2bf(sv[ct][r]);
        }
        #pragma unroll
        for (int oc = 0; oc < 8; ++oc) oacc[oc] *= alpha;
        // O += P V : A-frags from Pw, B-frags from Vlds
        bf16x8 pf0 = *(const bf16x8*)&Pw[(quad * 16 + lm) * 8];
        bf16x8 pf1 = *(const bf16x8*)&Pw[((4 + quad) * 16 + lm) * 8];
        #pragma unroll
        for (int oc = 0; oc < 8; ++oc) {
            bf16x8 v0 = *(const bf16x8*)&Vlds[((quad) * 128 + oc * 16 + lm) * 8];
            bf16x8 v1 = *(const bf16x8*)&Vlds[((4 + quad) * 128 + oc * 16 + lm) * 8];
            oacc[oc] = mfma16(pf0, v0, oacc[oc]);
            oacc[oc] = mfma16(pf1, v1, oacc[oc]);
        }
    }

    #pragma unroll
    for (int oc = 0; oc < 8; ++oc)
        #pragma unroll
        for (int r = 0; r < 4; ++r)
            Opart[po + (size_t)(wv * 16 + quad * 4 + r) * 128 + oc * 16 + lm]
                = f2bf(oacc[oc][r]);
    if (lm == 0)
        #pragma unroll
        for (int r = 0; r < 4; ++r) {
            const int row = wv * 16 + quad * 4 + r;
            Ml[pm + row] = m4[r];
            Ml[pm + 32 + row] = l4[r];
        }
}

// ---------------------------------------------------------------------------
// Merge the two KV-halves. grid 512 x 256 thr. thread: 1 row x 16 cols.
// ---------------------------------------------------------------------------
__global__ __launch_bounds__(256)
void fa_combine(const unsigned short* __restrict__ Opart, const float* __restrict__ Ml,
                unsigned short* __restrict__ O)
{
    const int bx = blockIdx.x;
    const int b = bx >> 7, qt = bx & 127;
    const int tid = threadIdx.x;
    const int r = tid >> 3, cg = tid & 7;
    const size_t base = ((size_t)(b * 128 + qt)) * 2 * 4096;
    const int pmb = (b * 128 + qt) * 2 * 64;
    const float m0 = Ml[pmb + r],      l0 = Ml[pmb + 32 + r];
    const float m1 = Ml[pmb + 64 + r], l1 = Ml[pmb + 96 + r];
    const float ms = fmaxf(m0, m1);
    float a0 = __expf(m0 - ms), a1 = __expf(m1 - ms);
    const float rl = 1.f / (a0 * l0 + a1 * l1);    // >= 1 always (see notes)
    a0 *= rl; a1 *= rl;
    const unsigned short* p0 = Opart + base + (size_t)r * 128 + cg * 16;
    const unsigned short* p1 = p0 + 4096;
    unsigned short* dst = O + ((size_t)b * 4096 + qt * 32 + r) * 128 + cg * 16;
    #pragma unroll
    for (int half = 0; half < 2; ++half) {
        bf16x8 x0 = *(const bf16x8*)(p0 + half * 8);
        bf16x8 x1 = *(const bf16x8*)(p1 + half * 8);
        bf16x8 o;
        #pragma unroll
        for (int e = 0; e < 8; ++e)
            o[e] = f2bf(bf2f((unsigned short)x0[e]) * a0
                      + bf2f((unsigned short)x1[e]) * a1);
        *(bf16x8*)(dst + half * 8) = o;
    }
}

// ---------------------------------------------------------------------------
// Output projection + bias (unchanged). grid (128,8) x 256 thr.
// ---------------------------------------------------------------------------
__global__ __launch_bounds__(256)
void gemm_out(const unsigned short* __restrict__ Ain, const float* __restrict__ W,
              const float* __restrict__ bias, float* __restrict__ out)
{
    __shared__ unsigned short Bsl[16 * 128 * 8];
    __shared__ unsigned short Asl[4 * 128 * 8];
    const int tid = threadIdx.x;
    const int mb = blockIdx.x * 128;
    const int nb = blockIdx.y * 128;
    const int wv = tid >> 6, lane = tid & 63;
    const int wr = (wv >> 1) * 64, wc = (wv & 1) * 64;
    const int lm = lane & 15, quad = lane >> 4;

    {
        const int r = tid >> 1;
        #pragma unroll
        for (int i = 0; i < 8; ++i) {
            const int c = (tid & 1) * 8 + i;
            const float* g = W + (size_t)(nb + r) * 128 + c * 8;
            float4 w0 = *(const float4*)g, w1 = *(const float4*)(g + 4);
            bf16x8 pw;
            pw[0] = (short)f2bf(w0.x); pw[1] = (short)f2bf(w0.y);
            pw[2] = (short)f2bf(w0.z); pw[3] = (short)f2bf(w0.w);
            pw[4] = (short)f2bf(w1.x); pw[5] = (short)f2bf(w1.y);
            pw[6] = (short)f2bf(w1.z); pw[7] = (short)f2bf(w1.w);
            *(bf16x8*)&Bsl[(c * 128 + r) * 8] = pw;
        }
    }

    f32x4 acc[4][4];
    #pragma unroll
    for (int i = 0; i < 4; ++i)
        #pragma unroll
        for (int j = 0; j < 4; ++j) acc[i][j] = f32x4{0.f, 0.f, 0.f, 0.f};

    for (int kt = 0; kt < 4; ++kt) {
        __syncthreads();
        #pragma unroll
        for (int i = 0; i < 2; ++i) {
            const int id = wv * 2 + i;
            const int c = id >> 1, h = id & 1;
            const unsigned short* g = Ain + (size_t)(mb + h * 64 + lane) * 128 + kt * 32 + c * 8;
            gl2lds16(g, &Asl[c * 1024 + h * 512]);
        }
        __syncthreads();
        bf16x8 af[4], bfr[4];
        #pragma unroll
        for (int i = 0; i < 4; ++i)
            af[i] = *(const bf16x8*)&Asl[(quad * 128 + wr + i * 16 + lm) * 8];
        #pragma unroll
        for (int j = 0; j < 4; ++j)
            bfr[j] = *(const bf16x8*)&Bsl[((kt * 4 + quad) * 128 + wc + j * 16 + lm) * 8];
        #pragma unroll
        for (int i = 0; i < 4; ++i)
            #pragma unroll
            for (int j = 0; j < 4; ++j)
                acc[i][j] = mfma16(af[i], bfr[j], acc[i][j]);
    }

    #pragma unroll
    for (int j = 0; j < 4; ++j) {
        const int col = nb + wc + j * 16 + lm;
        const float bv = bias[col];
        #pragma unroll
        for (int i = 0; i < 4; ++i)
            #pragma unroll
            for (int r = 0; r < 4; ++r) {
                const int m = mb + wr + i * 16 + quad * 4 + r;
                out[(size_t)m * 1024 + col] = acc[i][j][r] + bv;
            }
    }
}

// ---------------------------------------------------------------------------
extern "C" void kernel_launch(void* const* d_in, const int* in_sizes, int n_in,
                              void* d_out, int out_size, void* d_ws, size_t ws_size,
                              hipStream_t stream)
{
    (void)in_sizes; (void)n_in; (void)out_size; (void)ws_size;
    const float* x     = (const float*)d_in[0];
    const float* w_qkv = (const float*)d_in[1];
    const float* w_out = (const float*)d_in[2];
    const float* b_out = (const float*)d_in[3];
    float* out = (float*)d_out;
    unsigned short* ws = (unsigned short*)d_ws;

    const size_t NE = (size_t)16384 * 128;
    unsigned short* q  = ws;
    unsigned short* k  = ws + NE;
    unsigned short* v  = ws + 2 * NE;
    unsigned short* vt = ws + 3 * NE;
    unsigned short* o  = ws + 4 * NE;
    unsigned short* op = ws + 5 * NE;                 // Opart: 2*NE shorts (8 MB)
    float*          ml = (float*)(ws + 7 * NE);       // 64 K floats (256 KB)
    // total ws: 7*NE*2B + 256KB = 28.3 MB

    hipLaunchKernelGGL(gemm_qkv,    dim3(128, 3), dim3(256), 0, stream, x, w_qkv, q, k, v);
    hipLaunchKernelGGL(transpose_v, dim3(256),    dim3(256), 0, stream, v, vt);
    hipLaunchKernelGGL(flash_attn2, dim3(1024),   dim3(128), 0, stream, q, k, vt, op, ml);
    hipLaunchKernelGGL(fa_combine,  dim3(512),    dim3(256), 0, stream, op, ml, o);
    hipLaunchKernelGGL(gemm_out,    dim3(128, 8), dim3(256), 0, stream, o, w_out, b_out, out);
}

// Round 5
// 237.356 us; speedup vs baseline: 3.6382x; 1.1882x over previous
//
#include <hip/hip_runtime.h>
#include <math.h>

// ---------------------------------------------------------------------------
// bf16-MFMA pipeline v4 — frag-major global layouts for coalesced
// global_load_lds staging (fixes the 64-distinct-line scatter of v3):
//   gemm_qkv    : x fp32 -> Qfm/Kfm (frag-major 64-row tiles) + V plain
//   transpose_v : V plain -> Vfm (frag-major V^T tiles)
//   flash_attn3 : Br=64 (4 waves), Bc=64, KV-split x4, in-register softmax
//   fa_combine  : merge 4 splits -> Ofm
//   gemm_out    : Ofm x w_out^T + bias -> out fp32
// Layout: addr(tile,c,r,j) = ((tile*NC + c)*64 + r)*8 + j  (NC = K/8)
// ---------------------------------------------------------------------------

typedef __attribute__((ext_vector_type(8))) short bf16x8;
typedef __attribute__((ext_vector_type(4))) short bf16x4;
typedef __attribute__((ext_vector_type(4))) float f32x4;

#define FA_SCALE 0.08838834764831845f   // 128^-0.5

__device__ __forceinline__ unsigned short f2bf(float f) {
    union { float f; unsigned u; } v; v.f = f;
    unsigned r = v.u + 0x7FFFu + ((v.u >> 16) & 1u);    // RNE
    return (unsigned short)(r >> 16);
}
__device__ __forceinline__ float bf2f(unsigned short h) {
    union { unsigned u; float f; } v; v.u = ((unsigned)h) << 16;
    return v.f;
}
__device__ __forceinline__ f32x4 mfma16(bf16x8 a, bf16x8 b, f32x4 c) {
    return __builtin_amdgcn_mfma_f32_16x16x32_bf16(a, b, c, 0, 0, 0);
}
__device__ __forceinline__ void gl2lds16(const void* g, void* l) {
    __builtin_amdgcn_global_load_lds(
        (const __attribute__((address_space(1))) unsigned int*)g,
        (__attribute__((address_space(3))) unsigned int*)l, 16, 0, 0);
}
__device__ __forceinline__ f32x4 vmax4(f32x4 a, f32x4 b) {
    return f32x4{fmaxf(a[0], b[0]), fmaxf(a[1], b[1]),
                 fmaxf(a[2], b[2]), fmaxf(a[3], b[3])};
}

// ---------------------------------------------------------------------------
// QKV projection. BM=128,BN=128,BK=32. grid(128,3)x256.
// nb=0 -> Qfm, nb=128 -> Kfm (frag-major), nb=256 -> V plain [m][128].
// ---------------------------------------------------------------------------
__global__ __launch_bounds__(256)
void gemm_qkv(const float* __restrict__ X, const float* __restrict__ W,
              unsigned short* __restrict__ qfm, unsigned short* __restrict__ kfm,
              unsigned short* __restrict__ vpl)
{
    __shared__ unsigned short Asl[4 * 128 * 8];
    __shared__ unsigned short Bsl[4 * 128 * 8];
    const int tid = threadIdx.x;
    const int mb = blockIdx.x * 128;
    const int nb = blockIdx.y * 128;
    const int wv = tid >> 6, lane = tid & 63;
    const int wr = (wv >> 1) * 64, wc = (wv & 1) * 64;
    const int lm = lane & 15, quad = lane >> 4;
    const int sr = tid >> 2, sc = tid & 3;

    f32x4 acc[4][4];
    #pragma unroll
    for (int i = 0; i < 4; ++i)
        #pragma unroll
        for (int j = 0; j < 4; ++j) acc[i][j] = f32x4{0.f, 0.f, 0.f, 0.f};

    for (int kt = 0; kt < 1024; kt += 32) {
        __syncthreads();
        #pragma unroll
        for (int h = 0; h < 2; ++h) {
            const int row = sr + h * 64;
            const float* g = X + (size_t)(mb + row) * 1024 + kt + sc * 8;
            float4 x0 = *(const float4*)g, x1 = *(const float4*)(g + 4);
            bf16x8 pk;
            pk[0] = (short)f2bf(x0.x); pk[1] = (short)f2bf(x0.y);
            pk[2] = (short)f2bf(x0.z); pk[3] = (short)f2bf(x0.w);
            pk[4] = (short)f2bf(x1.x); pk[5] = (short)f2bf(x1.y);
            pk[6] = (short)f2bf(x1.z); pk[7] = (short)f2bf(x1.w);
            *(bf16x8*)&Asl[(sc * 128 + row) * 8] = pk;
            const float* gw = W + (size_t)(nb + row) * 1024 + kt + sc * 8;
            float4 w0 = *(const float4*)gw, w1 = *(const float4*)(gw + 4);
            bf16x8 pw;
            pw[0] = (short)f2bf(w0.x); pw[1] = (short)f2bf(w0.y);
            pw[2] = (short)f2bf(w0.z); pw[3] = (short)f2bf(w0.w);
            pw[4] = (short)f2bf(w1.x); pw[5] = (short)f2bf(w1.y);
            pw[6] = (short)f2bf(w1.z); pw[7] = (short)f2bf(w1.w);
            *(bf16x8*)&Bsl[(sc * 128 + row) * 8] = pw;
        }
        __syncthreads();
        bf16x8 af[4], bfr[4];
        #pragma unroll
        for (int i = 0; i < 4; ++i)
            af[i] = *(const bf16x8*)&Asl[(quad * 128 + wr + i * 16 + lm) * 8];
        #pragma unroll
        for (int j = 0; j < 4; ++j)
            bfr[j] = *(const bf16x8*)&Bsl[(quad * 128 + wc + j * 16 + lm) * 8];
        #pragma unroll
        for (int i = 0; i < 4; ++i)
            #pragma unroll
            for (int j = 0; j < 4; ++j)
                acc[i][j] = mfma16(af[i], bfr[j], acc[i][j]);
    }

    if (nb == 256) {                      // V: plain row-major
        #pragma unroll
        for (int i = 0; i < 4; ++i)
            #pragma unroll
            for (int j = 0; j < 4; ++j)
                #pragma unroll
                for (int r = 0; r < 4; ++r)
                    vpl[(size_t)(mb + wr + i * 16 + quad * 4 + r) * 128
                        + wc + j * 16 + lm] = f2bf(acc[i][j][r]);
    } else {                              // Q/K: frag-major 64-row tiles
        unsigned short* dst = (nb == 0) ? qfm : kfm;
        const int tile = (mb + wr) >> 6;
        #pragma unroll
        for (int i = 0; i < 4; ++i)
            #pragma unroll
            for (int j = 0; j < 4; ++j) {
                const size_t cb = (size_t)(tile * 16 + (wc >> 3) + j * 2 + (lm >> 3)) * 512
                                  + (lm & 7);
                #pragma unroll
                for (int r = 0; r < 4; ++r)
                    dst[cb + (i * 16 + quad * 4 + r) * 8] = f2bf(acc[i][j][r]);
            }
    }
}

// ---------------------------------------------------------------------------
// V plain -> Vfm: per (b, 64-key tile): addr = ((b*64+kt)*8 + c)*1024 + d*8 + j
// where key = kt*64 + c*8 + j, d in [0,128). grid 256 x 256 thr.
// ---------------------------------------------------------------------------
__global__ __launch_bounds__(256)
void transpose_v(const unsigned short* __restrict__ V, unsigned short* __restrict__ Vfm)
{
    __shared__ unsigned short T[128 * 72];   // [d][key-rel], stride 72
    const int tid = threadIdx.x;
    const int b  = blockIdx.x >> 6;
    const int kt = blockIdx.x & 63;
    const unsigned short* src = V + ((size_t)b * 4096 + kt * 64) * 128;
    #pragma unroll
    for (int i = 0; i < 4; ++i) {
        const int idx = tid + i * 256;
        const int key = idx >> 4, c8 = (idx & 15) * 8;
        bf16x8 d = *(const bf16x8*)(src + key * 128 + c8);
        #pragma unroll
        for (int e = 0; e < 8; ++e) T[(c8 + e) * 72 + key] = (unsigned short)d[e];
    }
    __syncthreads();
    unsigned short* dst = Vfm + (size_t)(b * 64 + kt) * 8192;
    #pragma unroll
    for (int i = 0; i < 4; ++i) {
        const int o = tid + i * 256;          // d = o&127, c = o>>7
        const int d = o & 127, c = o >> 7;
        bf16x8 x = *(const bf16x8*)&T[d * 72 + c * 8];
        *(bf16x8*)(dst + ((size_t)c * 128 + d) * 8) = x;   // coalesced store
    }
}

// ---------------------------------------------------------------------------
// Flash attention v3: 256 thr (4 waves), Br=64 (wave owns 16 rows), Bc=64.
// All staging fully coalesced from frag-major tiles. KV-split x4.
// LDS 40 KB -> 4 blocks/CU.
// ---------------------------------------------------------------------------
__global__ __launch_bounds__(256, 4)
void flash_attn3(const unsigned short* __restrict__ Qfm, const unsigned short* __restrict__ Kfm,
                 const unsigned short* __restrict__ Vfm,
                 unsigned short* __restrict__ Opart, float* __restrict__ Ml)
{
    __shared__ unsigned short Klds[8192];       // 16 KB: Q then K tiles
    __shared__ unsigned short Vlds[8192];       // 16 KB
    __shared__ unsigned short Plds[4][1024];    // per-wave P (A-frag), 8 KB

    const int tid = threadIdx.x;
    const int wv = tid >> 6, lane = tid & 63;
    const int lm = lane & 15, quad = lane >> 4;

    const int bx = blockIdx.x;
    const int b  = bx & 3;
    const int sp = (bx >> 2) & 3;
    const int qi = bx >> 4;                                  // 0..63
    const int qt = (qi & 1) ? (qi >> 1) : (63 - (qi >> 1));  // heavy/light pair
    const int n  = qt + 1;                                   // key tiles
    const int cnt = (n >> 2) + ((sp < (n & 3)) ? 1 : 0);
    const int ktb = sp * (n >> 2) + ((sp < (n & 3)) ? sp : (n & 3));
    const int kte = ktb + cnt;

    const size_t obase = (size_t)((b * 64 + qt) * 4 + sp) * 8192;
    const int    mlb   = ((b * 64 + qt) * 4 + sp) * 128;

    if (cnt == 0) {                      // neutral partial
        bf16x8 z = {0, 0, 0, 0, 0, 0, 0, 0};
        #pragma unroll
        for (int t = 0; t < 4; ++t)
            *(bf16x8*)&Opart[obase + (size_t)(tid + t * 256) * 8] = z;
        if (tid < 64) Ml[mlb + tid] = -INFINITY;
        else if (tid < 128) Ml[mlb + tid] = 0.f;
        return;
    }

    // stage Q tile (16 KB, 16 coalesced 1-KB pieces), pull frags to regs
    {
        const size_t qb = (size_t)(b * 64 + qt) * 8192;
        #pragma unroll
        for (int i = 0; i < 4; ++i) {
            const int pc = wv * 4 + i;
            gl2lds16(Qfm + qb + pc * 512 + lane * 8, &Klds[pc * 512]);
        }
    }
    __syncthreads();
    bf16x8 qf[4];
    #pragma unroll
    for (int c = 0; c < 4; ++c)
        qf[c] = *(const bf16x8*)&Klds[((c * 4 + quad) * 64 + wv * 16 + lm) * 8];

    f32x4 oacc[8];
    #pragma unroll
    for (int oc = 0; oc < 8; ++oc) oacc[oc] = f32x4{0.f, 0.f, 0.f, 0.f};
    f32x4 m4 = f32x4{-INFINITY, -INFINITY, -INFINITY, -INFINITY};
    f32x4 l4 = f32x4{0.f, 0.f, 0.f, 0.f};
    unsigned short* Pw = Plds[wv];

    for (int kt = ktb; kt < kte; ++kt) {
        __syncthreads();                 // prior-tile LDS consumers done (+Q frags)
        const size_t kb = (size_t)(b * 64 + kt) * 8192;
        #pragma unroll
        for (int i = 0; i < 4; ++i) {
            const int pc = wv * 4 + i;
            gl2lds16(Kfm + kb + pc * 512 + lane * 8, &Klds[pc * 512]);
            gl2lds16(Vfm + kb + pc * 512 + lane * 8, &Vlds[pc * 512]);
        }
        __syncthreads();                 // drain: K/V tiles ready

        // S = Q K^T : wave's 16 rows x 64 keys
        f32x4 sv[4];
        #pragma unroll
        for (int ct = 0; ct < 4; ++ct) {
            f32x4 a = f32x4{0.f, 0.f, 0.f, 0.f};
            #pragma unroll
            for (int c = 0; c < 4; ++c) {
                bf16x8 kf = *(const bf16x8*)&Klds[((c * 4 + quad) * 64 + ct * 16 + lm) * 8];
                a = mfma16(qf[c], kf, a);
            }
            sv[ct] = a * FA_SCALE;
        }
        if (kt == qt) {                  // diagonal tile: mask key > row
            #pragma unroll
            for (int ct = 0; ct < 4; ++ct) {
                const int dg = ct * 16 + lm - wv * 16 - quad * 4;
                #pragma unroll
                for (int rr = 0; rr < 4; ++rr)
                    if (dg > rr) sv[ct][rr] = -INFINITY;
            }
        }
        // online softmax (rows = quad's 16 lanes; in-quad butterfly)
        f32x4 rmax = vmax4(vmax4(sv[0], sv[1]), vmax4(sv[2], sv[3]));
        #pragma unroll
        for (int d = 1; d < 16; d <<= 1) {
            f32x4 o;
            #pragma unroll
            for (int e = 0; e < 4; ++e) o[e] = __shfl_xor(rmax[e], d);
            rmax = vmax4(rmax, o);
        }
        const f32x4 mnew = vmax4(m4, rmax);
        f32x4 alpha, rs = f32x4{0.f, 0.f, 0.f, 0.f};
        #pragma unroll
        for (int e = 0; e < 4; ++e) alpha[e] = __expf(m4[e] - mnew[e]);
        #pragma unroll
        for (int ct = 0; ct < 4; ++ct)
            #pragma unroll
            for (int rr = 0; rr < 4; ++rr) {
                const float p = __expf(sv[ct][rr] - mnew[rr]);
                sv[ct][rr] = p; rs[rr] += p;
            }
        #pragma unroll
        for (int d = 1; d < 16; d <<= 1) {
            f32x4 o;
            #pragma unroll
            for (int e = 0; e < 4; ++e) o[e] = __shfl_xor(rs[e], d);
            rs += o;
        }
        l4 = l4 * alpha + rs;
        m4 = mnew;
        // P -> wave-private LDS (A-frag layout), no barrier needed
        #pragma unroll
        for (int ct = 0; ct < 4; ++ct) {
            const int cb = ((ct * 2 + (lm >> 3)) * 16 + quad * 4) * 8 + (lm & 7);
            #pragma unroll
            for (int rr = 0; rr < 4; ++rr)
                Pw[cb + rr * 8] = f2bf(sv[ct][rr]);
        }
        #pragma unroll
        for (int oc = 0; oc < 8; ++oc) oacc[oc] *= alpha;
        // O += P V
        #pragma unroll
        for (int s = 0; s < 2; ++s) {
            bf16x8 pf = *(const bf16x8*)&Pw[((s * 4 + quad) * 16 + lm) * 8];
            #pragma unroll
            for (int oc = 0; oc < 8; ++oc) {
                bf16x8 vf = *(const bf16x8*)&Vlds[((s * 4 + quad) * 128 + oc * 16 + lm) * 8];
                oacc[oc] = mfma16(pf, vf, oacc[oc]);
            }
        }
    }

    // epilogue: Opart (frag-major granules) + Ml
    #pragma unroll
    for (int oc = 0; oc < 8; ++oc) {
        const size_t cb = obase + (size_t)((oc * 2 + (lm >> 3)) * 64
                          + wv * 16 + quad * 4) * 8 + (lm & 7);
        #pragma unroll
        for (int rr = 0; rr < 4; ++rr)
            Opart[cb + rr * 8] = f2bf(oacc[oc][rr]);
    }
    if (lm == 0)
        #pragma unroll
        for (int rr = 0; rr < 4; ++rr) {
            const int row = wv * 16 + quad * 4 + rr;
            Ml[mlb + row] = m4[rr];
            Ml[mlb + 64 + row] = l4[rr];
        }
}

// ---------------------------------------------------------------------------
// Merge 4 splits -> Ofm (frag-major). grid 256 (= b*64+qt) x 256 thr.
// ---------------------------------------------------------------------------
__global__ __launch_bounds__(256)
void fa_combine(const unsigned short* __restrict__ Opart, const float* __restrict__ Ml,
                unsigned short* __restrict__ Ofm)
{
    const int bq = blockIdx.x;
    const int tid = threadIdx.x;
    const size_t pbase = (size_t)bq * 4 * 8192;
    const int mlb = bq * 4 * 128;
    #pragma unroll
    for (int t = 0; t < 4; ++t) {
        const int g = tid + t * 256;          // granule: c = g>>6, r = g&63
        const int r = g & 63;
        float m[4], l[4];
        #pragma unroll
        for (int s = 0; s < 4; ++s) {
            m[s] = Ml[mlb + s * 128 + r];
            l[s] = Ml[mlb + s * 128 + 64 + r];
        }
        const float M = fmaxf(fmaxf(m[0], m[1]), fmaxf(m[2], m[3]));
        float a[4], den = 0.f;
        #pragma unroll
        for (int s = 0; s < 4; ++s) { a[s] = __expf(m[s] - M); den += a[s] * l[s]; }
        const float rsc = 1.f / den;
        float acc[8] = {};
        #pragma unroll
        for (int s = 0; s < 4; ++s) {
            bf16x8 x = *(const bf16x8*)&Opart[pbase + (size_t)s * 8192 + (size_t)g * 8];
            #pragma unroll
            for (int e = 0; e < 8; ++e) acc[e] += a[s] * bf2f((unsigned short)x[e]);
        }
        bf16x8 o;
        #pragma unroll
        for (int e = 0; e < 8; ++e) o[e] = f2bf(acc[e] * rsc);
        *(bf16x8*)&Ofm[(size_t)bq * 8192 + (size_t)g * 8] = o;   // coalesced
    }
}

// ---------------------------------------------------------------------------
// Output projection + bias. A from Ofm (coalesced staging). grid(128,8)x256.
// ---------------------------------------------------------------------------
__global__ __launch_bounds__(256)
void gemm_out(const unsigned short* __restrict__ Ain, const float* __restrict__ W,
              const float* __restrict__ bias, float* __restrict__ out)
{
    __shared__ unsigned short Bsl[16 * 128 * 8];   // W tile (K=128), 32 KB
    __shared__ unsigned short Asl[8 * 64 * 8];     // per-BK32 A (2 subtiles), 8 KB
    const int tid = threadIdx.x;
    const int mb = blockIdx.x * 128;
    const int nb = blockIdx.y * 128;
    const int wv = tid >> 6, lane = tid & 63;
    const int wr = (wv >> 1) * 64, wc = (wv & 1) * 64;
    const int lm = lane & 15, quad = lane >> 4;

    {   // stage W once (fp32 -> bf16)
        const int r = tid >> 1;
        #pragma unroll
        for (int i = 0; i < 8; ++i) {
            const int c = (tid & 1) * 8 + i;
            const float* g = W + (size_t)(nb + r) * 128 + c * 8;
            float4 w0 = *(const float4*)g, w1 = *(const float4*)(g + 4);
            bf16x8 pw;
            pw[0] = (short)f2bf(w0.x); pw[1] = (short)f2bf(w0.y);
            pw[2] = (short)f2bf(w0.z); pw[3] = (short)f2bf(w0.w);
            pw[4] = (short)f2bf(w1.x); pw[5] = (short)f2bf(w1.y);
            pw[6] = (short)f2bf(w1.z); pw[7] = (short)f2bf(w1.w);
            *(bf16x8*)&Bsl[(c * 128 + r) * 8] = pw;
        }
    }

    f32x4 acc[4][4];
    #pragma unroll
    for (int i = 0; i < 4; ++i)
        #pragma unroll
        for (int j = 0; j < 4; ++j) acc[i][j] = f32x4{0.f, 0.f, 0.f, 0.f};

    for (int kt = 0; kt < 4; ++kt) {
        __syncthreads();
        #pragma unroll
        for (int i = 0; i < 2; ++i) {
            const int id = wv * 2 + i;          // 0..7: subtile t, chunk kcl
            const int t = id >> 2, kcl = id & 3;
            gl2lds16(Ain + ((size_t)(mb >> 6) + t) * 8192 + (kt * 4 + kcl) * 512 + lane * 8,
                     &Asl[(t * 4 + kcl) * 512]);
        }
        __syncthreads();
        bf16x8 af[4], bfr[4];
        #pragma unroll
        for (int i = 0; i < 4; ++i)
            af[i] = *(const bf16x8*)&Asl[(((wv >> 1) * 4 + quad) * 64 + i * 16 + lm) * 8];
        #pragma unroll
        for (int j = 0; j < 4; ++j)
            bfr[j] = *(const bf16x8*)&Bsl[((kt * 4 + quad) * 128 + wc + j * 16 + lm) * 8];
        #pragma unroll
        for (int i = 0; i < 4; ++i)
            #pragma unroll
            for (int j = 0; j < 4; ++j)
                acc[i][j] = mfma16(af[i], bfr[j], acc[i][j]);
    }

    #pragma unroll
    for (int j = 0; j < 4; ++j) {
        const int col = nb + wc + j * 16 + lm;
        const float bv = bias[col];
        #pragma unroll
        for (int i = 0; i < 4; ++i)
            #pragma unroll
            for (int r = 0; r < 4; ++r) {
                const int m = mb + wr + i * 16 + quad * 4 + r;
                out[(size_t)m * 1024 + col] = acc[i][j][r] + bv;
            }
    }
}

// ---------------------------------------------------------------------------
extern "C" void kernel_launch(void* const* d_in, const int* in_sizes, int n_in,
                              void* d_out, int out_size, void* d_ws, size_t ws_size,
                              hipStream_t stream)
{
    (void)in_sizes; (void)n_in; (void)out_size; (void)ws_size;
    const float* x     = (const float*)d_in[0];
    const float* w_qkv = (const float*)d_in[1];
    const float* w_out = (const float*)d_in[2];
    const float* b_out = (const float*)d_in[3];
    float* out = (float*)d_out;
    unsigned short* ws = (unsigned short*)d_ws;

    const size_t NE = (size_t)16384 * 128;          // 2 097 152
    unsigned short* qfm = ws;                        // 4 MB (Ofm aliases after flash)
    unsigned short* kfm = ws + NE;                   // 4 MB
    unsigned short* vpl = ws + 2 * NE;               // 4 MB
    unsigned short* vfm = ws + 3 * NE;               // 4 MB
    unsigned short* op  = ws + 4 * NE;               // Opart 4*NE = 16.8 MB
    float*          ml  = (float*)(ws + 8 * NE);     // 131072 floats = 0.5 MB
    unsigned short* ofm = qfm;                       // alias: Qfm dead after flash

    hipLaunchKernelGGL(gemm_qkv,    dim3(128, 3), dim3(256), 0, stream, x, w_qkv, qfm, kfm, vpl);
    hipLaunchKernelGGL(transpose_v, dim3(256),    dim3(256), 0, stream, vpl, vfm);
    hipLaunchKernelGGL(flash_attn3, dim3(1024),   dim3(256), 0, stream, qfm, kfm, vfm, op, ml);
    hipLaunchKernelGGL(fa_combine,  dim3(256),    dim3(256), 0, stream, op, ml, ofm);
    hipLaunchKernelGGL(gemm_out,    dim3(128, 8), dim3(256), 0, stream, ofm, w_out, b_out, out);
}